// Round 1
// baseline (1359.565 us; speedup 1.0000x reference)
//
#include <hip/hip_runtime.h>
#include <hip/hip_bf16.h>
#include <math.h>

#define NHEAD 4
#define HC 256

// ---------------- generic fp32 GEMM: C = act(A@B + bias) ----------------
// mode 0: +bias; 1: +bias,relu; 2: +bias,relu,bn_eval(gamma,beta)
__global__ __launch_bounds__(256) void gemm_kernel(
    const float* __restrict__ A, const float* __restrict__ B,
    const float* __restrict__ bias, const float* __restrict__ gamma,
    const float* __restrict__ beta, float* __restrict__ Cm,
    int M, int N, int K, int ldc, int coloff, int mode)
{
  __shared__ float As[16][64 + 1];
  __shared__ float Bs[16][64 + 1];
  int bm = blockIdx.x * 64, bn = blockIdx.y * 64;
  int tid = threadIdx.x;
  int tr = tid >> 4, tc = tid & 15;
  float acc[4][4];
#pragma unroll
  for (int i = 0; i < 4; ++i)
#pragma unroll
    for (int j = 0; j < 4; ++j) acc[i][j] = 0.f;

  int lm = tid >> 2;          // 0..63  (A tile row)
  int lk = (tid & 3) * 4;     // 0,4,8,12 (A tile k)
  int ln = tid & 63;          // 0..63  (B tile col)
  int lkb = (tid >> 6) * 4;   // 0,4,8,12 (B tile k)

  for (int k0 = 0; k0 < K; k0 += 16) {
    int grow = bm + lm;
#pragma unroll
    for (int i = 0; i < 4; ++i) {
      int gk = k0 + lk + i;
      As[lk + i][lm] = (grow < M && gk < K) ? A[(long)grow * K + gk] : 0.f;
    }
    int gn = bn + ln;
#pragma unroll
    for (int i = 0; i < 4; ++i) {
      int gk = k0 + lkb + i;
      Bs[lkb + i][ln] = (gk < K && gn < N) ? B[(long)gk * N + gn] : 0.f;
    }
    __syncthreads();
#pragma unroll
    for (int kk = 0; kk < 16; ++kk) {
      float a[4], b[4];
#pragma unroll
      for (int i = 0; i < 4; ++i) a[i] = As[kk][tr * 4 + i];
#pragma unroll
      for (int j = 0; j < 4; ++j) b[j] = Bs[kk][tc * 4 + j];
#pragma unroll
      for (int i = 0; i < 4; ++i)
#pragma unroll
        for (int j = 0; j < 4; ++j) acc[i][j] = fmaf(a[i], b[j], acc[i][j]);
    }
    __syncthreads();
  }
  const float inv = rsqrtf(1.f + 1e-5f);
#pragma unroll
  for (int i = 0; i < 4; ++i) {
    int row = bm + tr * 4 + i;
    if (row >= M) continue;
#pragma unroll
    for (int j = 0; j < 4; ++j) {
      int col = bn + tc * 4 + j;
      if (col >= N) continue;
      float v = acc[i][j] + bias[col];
      if (mode >= 1) v = fmaxf(v, 0.f);
      if (mode == 2) v = v * (gamma[col] * inv) + beta[col];
      Cm[(long)row * ldc + coloff + col] = v;
    }
  }
}

// ---------------- CSR build ----------------
__global__ void deg_count_kernel(const int* __restrict__ dst, int* __restrict__ deg, int E)
{
  int e = blockIdx.x * blockDim.x + threadIdx.x;
  if (e < E) atomicAdd(&deg[dst[e]], 1);
}

__global__ __launch_bounds__(1024) void scan_kernel(
    const int* __restrict__ deg, int* __restrict__ ptr, int* __restrict__ cursor, int N)
{
  __shared__ int sums[1024];
  int t = threadIdx.x;
  int base = t * 32;
  int local[32];
  int s = 0;
#pragma unroll
  for (int i = 0; i < 32; ++i) {
    int v = (base + i < N) ? deg[base + i] : 0;
    local[i] = v; s += v;
  }
  sums[t] = s;
  __syncthreads();
  for (int off = 1; off < 1024; off <<= 1) {
    int v = (t >= off) ? sums[t - off] : 0;
    __syncthreads();
    sums[t] += v;
    __syncthreads();
  }
  int excl = sums[t] - s;
  for (int i = 0; i < 32; ++i) {
    if (base + i < N) { ptr[base + i] = excl; cursor[base + i] = excl; excl += local[i]; }
  }
  if (t == 1023) ptr[N] = sums[1023];
}

__global__ void fill_kernel(const int* __restrict__ dst, int* __restrict__ cursor,
                            int* __restrict__ eid, int E)
{
  int e = blockIdx.x * blockDim.x + threadIdx.x;
  if (e < E) {
    int pos = atomicAdd(&cursor[dst[e]], 1);
    eid[pos] = e;
  }
}

// ---------------- GATv2 aggregation: one wave per node ----------------
// lane = channel c (0..63); 4 heads in registers; online softmax over
// incoming edges + trailing self-loop with mean edge_attr.
__global__ __launch_bounds__(256) void gat_kernel(
    const float* __restrict__ xl, const float* __restrict__ xr,
    const float* __restrict__ edge_attr, const int* __restrict__ src_idx,
    const int* __restrict__ csr_ptr, const int* __restrict__ csr_eid,
    const float* __restrict__ We, const float* __restrict__ att,
    const float* __restrict__ bias, float* __restrict__ out, int N)
{
  int lane = threadIdx.x & 63;
  int node = blockIdx.x * 4 + (threadIdx.x >> 6);
  if (node >= N) return;

  float attv[NHEAD], xri[NHEAD], WeR[8][NHEAD];
#pragma unroll
  for (int h = 0; h < NHEAD; ++h) {
    attv[h] = att[h * 64 + lane];
    xri[h] = xr[(long)node * HC + h * 64 + lane];
  }
#pragma unroll
  for (int d = 0; d < 8; ++d)
#pragma unroll
    for (int h = 0; h < NHEAD; ++h) WeR[d][h] = We[d * HC + h * 64 + lane];

  float rmax[NHEAD], rsum[NHEAD], acc[NHEAD];
#pragma unroll
  for (int h = 0; h < NHEAD; ++h) { rmax[h] = -INFINITY; rsum[h] = 0.f; acc[h] = 0.f; }
  float ea_sum[8];
#pragma unroll
  for (int d = 0; d < 8; ++d) ea_sum[d] = 0.f;

  int p0 = csr_ptr[node], p1 = csr_ptr[node + 1];

  for (int k = p0; k <= p1; ++k) {   // k==p1 is the self loop
    int s;
    float ea[8];
    if (k < p1) {
      int e = csr_eid[k];
      s = src_idx[e];
#pragma unroll
      for (int d = 0; d < 8; ++d) { ea[d] = edge_attr[(long)e * 8 + d]; ea_sum[d] += ea[d]; }
    } else {
      s = node;
      float invd = 1.f / (float)((p1 - p0) > 1 ? (p1 - p0) : 1);
#pragma unroll
      for (int d = 0; d < 8; ++d) ea[d] = ea_sum[d] * invd;
    }
    float xls[NHEAD], logit[NHEAD];
#pragma unroll
    for (int h = 0; h < NHEAD; ++h) xls[h] = xl[(long)s * HC + h * 64 + lane];
#pragma unroll
    for (int h = 0; h < NHEAD; ++h) {
      float ee = 0.f;
#pragma unroll
      for (int d = 0; d < 8; ++d) ee = fmaf(ea[d], WeR[d][h], ee);
      float m = xls[h] + xri[h] + ee;
      m = (m > 0.f) ? m : 0.2f * m;
      float t = m * attv[h];
#pragma unroll
      for (int off = 32; off > 0; off >>= 1) t += __shfl_xor(t, off, 64);
      logit[h] = t;
    }
#pragma unroll
    for (int h = 0; h < NHEAD; ++h) {
      float nm = fmaxf(rmax[h], logit[h]);
      float sc = __expf(rmax[h] - nm);
      float p = __expf(logit[h] - nm);
      rsum[h] = rsum[h] * sc + p;
      acc[h] = fmaf(p, xls[h], acc[h] * sc);
      rmax[h] = nm;
    }
  }
#pragma unroll
  for (int h = 0; h < NHEAD; ++h) {
    float v = acc[h] / rsum[h] + bias[h * 64 + lane];
    out[(long)node * HC + h * 64 + lane] = fmaxf(v, 0.f);
  }
}

// ---------------- global max pool (relu'd inputs => bits compare ok) ----------------
__global__ void pool_kernel(const float* __restrict__ h, const int* __restrict__ batch,
                            unsigned int* __restrict__ xg, long total)
{
  long i = (long)blockIdx.x * blockDim.x + threadIdx.x;
  if (i < total) {
    int node = (int)(i >> 8);
    int col = (int)(i & 255);
    atomicMax(&xg[(long)batch[node] * HC + col], __float_as_uint(h[i]));
  }
}

extern "C" void kernel_launch(void* const* d_in, const int* in_sizes, int n_in,
                              void* d_out, int out_size, void* d_ws, size_t ws_size,
                              hipStream_t stream)
{
  const float* x          = (const float*)d_in[0];
  const int*   edge_index = (const int*)d_in[1];
  const float* edge_attr  = (const float*)d_in[2];
  const int*   batch      = (const int*)d_in[3];
  const float* fp         = (const float*)d_in[4];
  const float* desc       = (const float*)d_in[5];
  const float *c1_Wl = (const float*)d_in[6],  *c1_bl = (const float*)d_in[7],
              *c1_Wr = (const float*)d_in[8],  *c1_br = (const float*)d_in[9],
              *c1_We = (const float*)d_in[10], *c1_att = (const float*)d_in[11],
              *c1_bias = (const float*)d_in[12];
  const float *c2_Wl = (const float*)d_in[13], *c2_bl = (const float*)d_in[14],
              *c2_Wr = (const float*)d_in[15], *c2_br = (const float*)d_in[16],
              *c2_We = (const float*)d_in[17], *c2_att = (const float*)d_in[18],
              *c2_bias = (const float*)d_in[19];
  const float *gW = (const float*)d_in[20], *gb = (const float*)d_in[21],
              *g_gn = (const float*)d_in[22], *g_bt = (const float*)d_in[23];
  const float *fW = (const float*)d_in[24], *fb = (const float*)d_in[25],
              *f_gn = (const float*)d_in[26], *f_bt = (const float*)d_in[27];
  const float *dW = (const float*)d_in[28], *db = (const float*)d_in[29],
              *d_gn = (const float*)d_in[30], *d_bt = (const float*)d_in[31];
  const float *k1W = (const float*)d_in[32], *k1b = (const float*)d_in[33],
              *k1_gn = (const float*)d_in[34], *k1_bt = (const float*)d_in[35];
  const float *k2W = (const float*)d_in[36], *k2b = (const float*)d_in[37],
              *k2_gn = (const float*)d_in[38], *k2_bt = (const float*)d_in[39];
  const float *k3W = (const float*)d_in[40], *k3b = (const float*)d_in[41];

  const int N = in_sizes[0] / 32;       // 32768
  const int E = in_sizes[1] / 2;        // 262144
  const int G = in_sizes[4] / 2048;     // 1024
  const int FIN = 32, FPIN = 2048;
  const int DIN = in_sizes[5] / G;      // 200

  char* ws = (char*)d_ws;
  size_t off = 0;
  auto alloc = [&](size_t bytes) {
    void* p = ws + off;
    off = (off + bytes + 255) & ~(size_t)255;
    return p;
  };
  float* xl      = (float*)alloc((size_t)N * HC * 4);
  float* xr      = (float*)alloc((size_t)N * HC * 4);
  float* hbuf    = (float*)alloc((size_t)N * HC * 4);
  float* xg      = (float*)alloc((size_t)G * HC * 4);
  float* zbuf    = (float*)alloc((size_t)G * 384 * 4);
  float* z1      = (float*)alloc((size_t)G * 192 * 4);
  float* z2      = (float*)alloc((size_t)G * 96 * 4);
  int*   deg     = (int*)alloc((size_t)N * 4);
  int*   csr_ptr = (int*)alloc((size_t)(N + 1) * 4);
  int*   cursor  = (int*)alloc((size_t)N * 4);
  int*   csr_eid = (int*)alloc((size_t)E * 4);
  (void)ws_size;

  const int* srcp = edge_index;
  const int* dstp = edge_index + E;

  hipMemsetAsync(deg, 0, (size_t)N * 4, stream);
  hipMemsetAsync(xg, 0, (size_t)G * HC * 4, stream);

  deg_count_kernel<<<(E + 255) / 256, 256, 0, stream>>>(dstp, deg, E);
  scan_kernel<<<1, 1024, 0, stream>>>(deg, csr_ptr, cursor, N);
  fill_kernel<<<(E + 255) / 256, 256, 0, stream>>>(dstp, cursor, csr_eid, E);

  dim3 gN((N + 63) / 64, (HC + 63) / 64);
  // layer 1 transforms
  gemm_kernel<<<gN, 256, 0, stream>>>(x, c1_Wl, c1_bl, nullptr, nullptr, xl, N, HC, FIN, HC, 0, 0);
  gemm_kernel<<<gN, 256, 0, stream>>>(x, c1_Wr, c1_br, nullptr, nullptr, xr, N, HC, FIN, HC, 0, 0);
  gat_kernel<<<(N + 3) / 4, 256, 0, stream>>>(xl, xr, edge_attr, srcp, csr_ptr, csr_eid,
                                              c1_We, c1_att, c1_bias, hbuf, N);
  // layer 2 transforms
  gemm_kernel<<<gN, 256, 0, stream>>>(hbuf, c2_Wl, c2_bl, nullptr, nullptr, xl, N, HC, HC, HC, 0, 0);
  gemm_kernel<<<gN, 256, 0, stream>>>(hbuf, c2_Wr, c2_br, nullptr, nullptr, xr, N, HC, HC, HC, 0, 0);
  gat_kernel<<<(N + 3) / 4, 256, 0, stream>>>(xl, xr, edge_attr, srcp, csr_ptr, csr_eid,
                                              c2_We, c2_att, c2_bias, hbuf, N);

  long total = (long)N * HC;
  pool_kernel<<<(int)((total + 255) / 256), 256, 0, stream>>>(hbuf, batch, (unsigned int*)xg, total);

  // readout branches -> concat buffer zbuf[G,384]
  gemm_kernel<<<dim3((G + 63) / 64, 1), 256, 0, stream>>>(xg, gW, gb, g_gn, g_bt, zbuf, G, 64, HC, 384, 0, 2);
  gemm_kernel<<<dim3((G + 63) / 64, 4), 256, 0, stream>>>(fp, fW, fb, f_gn, f_bt, zbuf, G, 256, FPIN, 384, 64, 2);
  gemm_kernel<<<dim3((G + 63) / 64, 1), 256, 0, stream>>>(desc, dW, db, d_gn, d_bt, zbuf, G, 64, DIN, 384, 320, 2);
  // MLP head
  gemm_kernel<<<dim3((G + 63) / 64, 3), 256, 0, stream>>>(zbuf, k1W, k1b, k1_gn, k1_bt, z1, G, 192, 384, 192, 0, 2);
  gemm_kernel<<<dim3((G + 63) / 64, 2), 256, 0, stream>>>(z1, k2W, k2b, k2_gn, k2_bt, z2, G, 96, 192, 96, 0, 2);
  gemm_kernel<<<dim3((G + 63) / 64, 1), 256, 0, stream>>>(z2, k3W, k3b, nullptr, nullptr, (float*)d_out, G, 12, 96, 12, 0, 0);
}

// Round 2
// 977.888 us; speedup vs baseline: 1.3903x; 1.3903x over previous
//
#include <hip/hip_runtime.h>
#include <hip/hip_bf16.h>
#include <math.h>

#define NHEAD 4
#define HC 256

// ---------------- generic fp32 GEMM: C = act(A@B + bias) ----------------
// mode 0: +bias; 1: +bias,relu; 2: +bias,relu,bn_eval(gamma,beta)
__global__ __launch_bounds__(256) void gemm_kernel(
    const float* __restrict__ A, const float* __restrict__ B,
    const float* __restrict__ bias, const float* __restrict__ gamma,
    const float* __restrict__ beta, float* __restrict__ Cm,
    int M, int N, int K, int ldc, int coloff, int mode)
{
  __shared__ float As[16][64 + 1];
  __shared__ float Bs[16][64 + 1];
  int bm = blockIdx.x * 64, bn = blockIdx.y * 64;
  int tid = threadIdx.x;
  int tr = tid >> 4, tc = tid & 15;
  float acc[4][4];
#pragma unroll
  for (int i = 0; i < 4; ++i)
#pragma unroll
    for (int j = 0; j < 4; ++j) acc[i][j] = 0.f;

  int lm = tid >> 2;          // 0..63  (A tile row)
  int lk = (tid & 3) * 4;     // 0,4,8,12 (A tile k)
  int ln = tid & 63;          // 0..63  (B tile col)
  int lkb = (tid >> 6) * 4;   // 0,4,8,12 (B tile k)

  for (int k0 = 0; k0 < K; k0 += 16) {
    int grow = bm + lm;
#pragma unroll
    for (int i = 0; i < 4; ++i) {
      int gk = k0 + lk + i;
      As[lk + i][lm] = (grow < M && gk < K) ? A[(long)grow * K + gk] : 0.f;
    }
    int gn = bn + ln;
#pragma unroll
    for (int i = 0; i < 4; ++i) {
      int gk = k0 + lkb + i;
      Bs[lkb + i][ln] = (gk < K && gn < N) ? B[(long)gk * N + gn] : 0.f;
    }
    __syncthreads();
#pragma unroll
    for (int kk = 0; kk < 16; ++kk) {
      float a[4], b[4];
#pragma unroll
      for (int i = 0; i < 4; ++i) a[i] = As[kk][tr * 4 + i];
#pragma unroll
      for (int j = 0; j < 4; ++j) b[j] = Bs[kk][tc * 4 + j];
#pragma unroll
      for (int i = 0; i < 4; ++i)
#pragma unroll
        for (int j = 0; j < 4; ++j) acc[i][j] = fmaf(a[i], b[j], acc[i][j]);
    }
    __syncthreads();
  }
  const float inv = rsqrtf(1.f + 1e-5f);
#pragma unroll
  for (int i = 0; i < 4; ++i) {
    int row = bm + tr * 4 + i;
    if (row >= M) continue;
#pragma unroll
    for (int j = 0; j < 4; ++j) {
      int col = bn + tc * 4 + j;
      if (col >= N) continue;
      float v = acc[i][j] + bias[col];
      if (mode >= 1) v = fmaxf(v, 0.f);
      if (mode == 2) v = v * (gamma[col] * inv) + beta[col];
      Cm[(long)row * ldc + coloff + col] = v;
    }
  }
}

// ---------------- skinny GEMM with split-K -> partial slices ----------------
// Output tile 16(M) x 64(N); grid.z = split index s over K-chunk Kc.
// Each split writes its own dense M x N slice: P[s*M*N + row*N + col].
__global__ __launch_bounds__(256) void gemm_sk_kernel(
    const float* __restrict__ A, const float* __restrict__ B,
    float* __restrict__ P, int M, int N, int K, int Kc)
{
  __shared__ float As[16][17];
  __shared__ float Bs[16][65];
  int bm = blockIdx.x * 16, bn = blockIdx.y * 64;
  int s = blockIdx.z;
  int kb = s * Kc;
  int ke = min(K, kb + Kc);
  int tid = threadIdx.x;
  int tc = tid & 63;        // col within tile
  int trq = tid >> 6;       // 0..3 -> rows trq*4 .. trq*4+3
  int ar = tid >> 4;        // A-load row 0..15
  int ak = tid & 15;        // A-load k
  float acc[4] = {0.f, 0.f, 0.f, 0.f};

  for (int k0 = kb; k0 < ke; k0 += 16) {
    int gm = bm + ar, gk = k0 + ak;
    As[ak][ar] = (gm < M && gk < ke) ? A[(long)gm * K + gk] : 0.f;
    int gn = bn + tc;
#pragma unroll
    for (int i = 0; i < 4; ++i) {
      int kk = trq * 4 + i;
      int gkb = k0 + kk;
      Bs[kk][tc] = (gkb < ke && gn < N) ? B[(long)gkb * N + gn] : 0.f;
    }
    __syncthreads();
#pragma unroll
    for (int kk = 0; kk < 16; ++kk) {
      float b = Bs[kk][tc];
#pragma unroll
      for (int i = 0; i < 4; ++i) acc[i] = fmaf(As[kk][trq * 4 + i], b, acc[i]);
    }
    __syncthreads();
  }
  int col = bn + tc;
  if (col < N) {
#pragma unroll
    for (int i = 0; i < 4; ++i) {
      int row = bm + trq * 4 + i;
      if (row < M) P[(long)s * M * N + (long)row * N + col] = acc[i];
    }
  }
}

// epilogue: sum S partial slices, +bias [, relu [, bn]] -> Cm[row*ldc+coloff+col]
__global__ __launch_bounds__(256) void epilogue_kernel(
    const float* __restrict__ P, const float* __restrict__ bias,
    const float* __restrict__ gamma, const float* __restrict__ beta,
    float* __restrict__ Cm, int M, int N, int S, int ldc, int coloff, int mode)
{
  int idx = blockIdx.x * 256 + threadIdx.x;
  if (idx >= M * N) return;
  int row = idx / N, col = idx - row * N;
  float v = 0.f;
  for (int s = 0; s < S; ++s) v += P[(long)s * M * N + idx];
  v += bias[col];
  if (mode >= 1) v = fmaxf(v, 0.f);
  if (mode == 2) {
    const float inv = rsqrtf(1.f + 1e-5f);
    v = v * (gamma[col] * inv) + beta[col];
  }
  Cm[(long)row * ldc + coloff + col] = v;
}

// ---------------- CSR build ----------------
__global__ void deg_count_kernel(const int* __restrict__ dst, int* __restrict__ deg, int E)
{
  int e = blockIdx.x * blockDim.x + threadIdx.x;
  if (e < E) atomicAdd(&deg[dst[e]], 1);
}

__global__ __launch_bounds__(1024) void scan_kernel(
    const int* __restrict__ deg, int* __restrict__ ptr, int* __restrict__ cursor, int N)
{
  __shared__ int sums[1024];
  int t = threadIdx.x;
  int base = t * 32;
  int local[32];
  int s = 0;
#pragma unroll
  for (int i = 0; i < 32; ++i) {
    int v = (base + i < N) ? deg[base + i] : 0;
    local[i] = v; s += v;
  }
  sums[t] = s;
  __syncthreads();
  for (int off = 1; off < 1024; off <<= 1) {
    int v = (t >= off) ? sums[t - off] : 0;
    __syncthreads();
    sums[t] += v;
    __syncthreads();
  }
  int excl = sums[t] - s;
  for (int i = 0; i < 32; ++i) {
    if (base + i < N) { ptr[base + i] = excl; cursor[base + i] = excl; excl += local[i]; }
  }
  if (t == 1023) ptr[N] = sums[1023];
}

__global__ void fill_kernel(const int* __restrict__ dst, int* __restrict__ cursor,
                            int* __restrict__ eid, int E)
{
  int e = blockIdx.x * blockDim.x + threadIdx.x;
  if (e < E) {
    int pos = atomicAdd(&cursor[dst[e]], 1);
    eid[pos] = e;
  }
}

// ---------------- GATv2 aggregation: one wave per node ----------------
__global__ __launch_bounds__(256) void gat_kernel(
    const float* __restrict__ xl, const float* __restrict__ xr,
    const float* __restrict__ edge_attr, const int* __restrict__ src_idx,
    const int* __restrict__ csr_ptr, const int* __restrict__ csr_eid,
    const float* __restrict__ We, const float* __restrict__ att,
    const float* __restrict__ bias, float* __restrict__ out, int N)
{
  int lane = threadIdx.x & 63;
  int node = blockIdx.x * 4 + (threadIdx.x >> 6);
  if (node >= N) return;

  float attv[NHEAD], xri[NHEAD], WeR[8][NHEAD];
#pragma unroll
  for (int h = 0; h < NHEAD; ++h) {
    attv[h] = att[h * 64 + lane];
    xri[h] = xr[(long)node * HC + h * 64 + lane];
  }
#pragma unroll
  for (int d = 0; d < 8; ++d)
#pragma unroll
    for (int h = 0; h < NHEAD; ++h) WeR[d][h] = We[d * HC + h * 64 + lane];

  float rmax[NHEAD], rsum[NHEAD], acc[NHEAD];
#pragma unroll
  for (int h = 0; h < NHEAD; ++h) { rmax[h] = -INFINITY; rsum[h] = 0.f; acc[h] = 0.f; }
  float ea_sum[8];
#pragma unroll
  for (int d = 0; d < 8; ++d) ea_sum[d] = 0.f;

  int p0 = csr_ptr[node], p1 = csr_ptr[node + 1];

  for (int k = p0; k <= p1; ++k) {   // k==p1 is the self loop
    int s;
    float ea[8];
    if (k < p1) {
      int e = csr_eid[k];
      s = src_idx[e];
#pragma unroll
      for (int d = 0; d < 8; ++d) { ea[d] = edge_attr[(long)e * 8 + d]; ea_sum[d] += ea[d]; }
    } else {
      s = node;
      float invd = 1.f / (float)((p1 - p0) > 1 ? (p1 - p0) : 1);
#pragma unroll
      for (int d = 0; d < 8; ++d) ea[d] = ea_sum[d] * invd;
    }
    float xls[NHEAD], logit[NHEAD];
#pragma unroll
    for (int h = 0; h < NHEAD; ++h) xls[h] = xl[(long)s * HC + h * 64 + lane];
#pragma unroll
    for (int h = 0; h < NHEAD; ++h) {
      float ee = 0.f;
#pragma unroll
      for (int d = 0; d < 8; ++d) ee = fmaf(ea[d], WeR[d][h], ee);
      float m = xls[h] + xri[h] + ee;
      m = (m > 0.f) ? m : 0.2f * m;
      float t = m * attv[h];
#pragma unroll
      for (int off = 32; off > 0; off >>= 1) t += __shfl_xor(t, off, 64);
      logit[h] = t;
    }
#pragma unroll
    for (int h = 0; h < NHEAD; ++h) {
      float nm = fmaxf(rmax[h], logit[h]);
      float sc = __expf(rmax[h] - nm);
      float p = __expf(logit[h] - nm);
      rsum[h] = rsum[h] * sc + p;
      acc[h] = fmaf(p, xls[h], acc[h] * sc);
      rmax[h] = nm;
    }
  }
#pragma unroll
  for (int h = 0; h < NHEAD; ++h) {
    float v = acc[h] / rsum[h] + bias[h * 64 + lane];
    out[(long)node * HC + h * 64 + lane] = fmaxf(v, 0.f);
  }
}

// ---------------- global max pool (relu'd inputs => bits compare ok) ----------------
__global__ void pool_kernel(const float* __restrict__ h, const int* __restrict__ batch,
                            unsigned int* __restrict__ xg, long total)
{
  long i = (long)blockIdx.x * blockDim.x + threadIdx.x;
  if (i < total) {
    int node = (int)(i >> 8);
    int col = (int)(i & 255);
    atomicMax(&xg[(long)batch[node] * HC + col], __float_as_uint(h[i]));
  }
}

extern "C" void kernel_launch(void* const* d_in, const int* in_sizes, int n_in,
                              void* d_out, int out_size, void* d_ws, size_t ws_size,
                              hipStream_t stream)
{
  const float* x          = (const float*)d_in[0];
  const int*   edge_index = (const int*)d_in[1];
  const float* edge_attr  = (const float*)d_in[2];
  const int*   batch      = (const int*)d_in[3];
  const float* fp         = (const float*)d_in[4];
  const float* desc       = (const float*)d_in[5];
  const float *c1_Wl = (const float*)d_in[6],  *c1_bl = (const float*)d_in[7],
              *c1_Wr = (const float*)d_in[8],  *c1_br = (const float*)d_in[9],
              *c1_We = (const float*)d_in[10], *c1_att = (const float*)d_in[11],
              *c1_bias = (const float*)d_in[12];
  const float *c2_Wl = (const float*)d_in[13], *c2_bl = (const float*)d_in[14],
              *c2_Wr = (const float*)d_in[15], *c2_br = (const float*)d_in[16],
              *c2_We = (const float*)d_in[17], *c2_att = (const float*)d_in[18],
              *c2_bias = (const float*)d_in[19];
  const float *gW = (const float*)d_in[20], *gb = (const float*)d_in[21],
              *g_gn = (const float*)d_in[22], *g_bt = (const float*)d_in[23];
  const float *fW = (const float*)d_in[24], *fb = (const float*)d_in[25],
              *f_gn = (const float*)d_in[26], *f_bt = (const float*)d_in[27];
  const float *dW = (const float*)d_in[28], *db = (const float*)d_in[29],
              *d_gn = (const float*)d_in[30], *d_bt = (const float*)d_in[31];
  const float *k1W = (const float*)d_in[32], *k1b = (const float*)d_in[33],
              *k1_gn = (const float*)d_in[34], *k1_bt = (const float*)d_in[35];
  const float *k2W = (const float*)d_in[36], *k2b = (const float*)d_in[37],
              *k2_gn = (const float*)d_in[38], *k2_bt = (const float*)d_in[39];
  const float *k3W = (const float*)d_in[40], *k3b = (const float*)d_in[41];

  const int N = in_sizes[0] / 32;       // 32768
  const int E = in_sizes[1] / 2;        // 262144
  const int G = in_sizes[4] / 2048;     // 1024
  const int FIN = 32, FPIN = 2048;
  const int DIN = in_sizes[5] / G;      // 200

  char* ws = (char*)d_ws;
  size_t off = 0;
  auto alloc = [&](size_t bytes) {
    void* p = ws + off;
    off = (off + bytes + 255) & ~(size_t)255;
    return p;
  };
  float* xl      = (float*)alloc((size_t)N * HC * 4);
  float* xr      = (float*)alloc((size_t)N * HC * 4);
  float* hbuf    = (float*)alloc((size_t)N * HC * 4);
  float* xg      = (float*)alloc((size_t)G * HC * 4);
  float* zbuf    = (float*)alloc((size_t)G * 384 * 4);
  float* z1      = (float*)alloc((size_t)G * 192 * 4);
  float* z2      = (float*)alloc((size_t)G * 96 * 4);
  int*   deg     = (int*)alloc((size_t)N * 4);
  int*   csr_ptr = (int*)alloc((size_t)(N + 1) * 4);
  int*   cursor  = (int*)alloc((size_t)N * 4);
  int*   csr_eid = (int*)alloc((size_t)E * 4);
  // split-K partial buffers
  float* P_fp    = (float*)alloc((size_t)G * 256 * 8 * 4);   // 8 MB
  float* P_g     = (float*)alloc((size_t)G * 64 * 4 * 4);
  float* P_d     = (float*)alloc((size_t)G * 64 * 4 * 4);
  float* P_k1    = (float*)alloc((size_t)G * 192 * 2 * 4);
  float* P_k2    = (float*)alloc((size_t)G * 96 * 2 * 4);
  float* P_k3    = (float*)alloc((size_t)G * 12 * 1 * 4);
  (void)ws_size;

  const int* srcp = edge_index;
  const int* dstp = edge_index + E;

  hipMemsetAsync(deg, 0, (size_t)N * 4, stream);
  hipMemsetAsync(xg, 0, (size_t)G * HC * 4, stream);

  deg_count_kernel<<<(E + 255) / 256, 256, 0, stream>>>(dstp, deg, E);
  scan_kernel<<<1, 1024, 0, stream>>>(deg, csr_ptr, cursor, N);
  fill_kernel<<<(E + 255) / 256, 256, 0, stream>>>(dstp, cursor, csr_eid, E);

  // fp / desc branches are independent of the graph pipeline; issue early.
  gemm_sk_kernel<<<dim3(G / 16, 4, 8), 256, 0, stream>>>(fp, fW, P_fp, G, 256, FPIN, 256);
  epilogue_kernel<<<(G * 256 + 255) / 256, 256, 0, stream>>>(P_fp, fb, f_gn, f_bt, zbuf, G, 256, 8, 384, 64, 2);
  gemm_sk_kernel<<<dim3(G / 16, 1, 4), 256, 0, stream>>>(desc, dW, P_d, G, 64, DIN, 50);
  epilogue_kernel<<<(G * 64 + 255) / 256, 256, 0, stream>>>(P_d, db, d_gn, d_bt, zbuf, G, 64, 4, 384, 320, 2);

  dim3 gN((N + 63) / 64, (HC + 63) / 64);
  // layer 1 transforms
  gemm_kernel<<<gN, 256, 0, stream>>>(x, c1_Wl, c1_bl, nullptr, nullptr, xl, N, HC, FIN, HC, 0, 0);
  gemm_kernel<<<gN, 256, 0, stream>>>(x, c1_Wr, c1_br, nullptr, nullptr, xr, N, HC, FIN, HC, 0, 0);
  gat_kernel<<<(N + 3) / 4, 256, 0, stream>>>(xl, xr, edge_attr, srcp, csr_ptr, csr_eid,
                                              c1_We, c1_att, c1_bias, hbuf, N);
  // layer 2 transforms
  gemm_kernel<<<gN, 256, 0, stream>>>(hbuf, c2_Wl, c2_bl, nullptr, nullptr, xl, N, HC, HC, HC, 0, 0);
  gemm_kernel<<<gN, 256, 0, stream>>>(hbuf, c2_Wr, c2_br, nullptr, nullptr, xr, N, HC, HC, HC, 0, 0);
  gat_kernel<<<(N + 3) / 4, 256, 0, stream>>>(xl, xr, edge_attr, srcp, csr_ptr, csr_eid,
                                              c2_We, c2_att, c2_bias, hbuf, N);

  long total = (long)N * HC;
  pool_kernel<<<(int)((total + 255) / 256), 256, 0, stream>>>(hbuf, batch, (unsigned int*)xg, total);

  // g branch (needs xg)
  gemm_sk_kernel<<<dim3(G / 16, 1, 4), 256, 0, stream>>>(xg, gW, P_g, G, 64, HC, 64);
  epilogue_kernel<<<(G * 64 + 255) / 256, 256, 0, stream>>>(P_g, gb, g_gn, g_bt, zbuf, G, 64, 4, 384, 0, 2);

  // MLP head
  gemm_sk_kernel<<<dim3(G / 16, 3, 2), 256, 0, stream>>>(zbuf, k1W, P_k1, G, 192, 384, 192);
  epilogue_kernel<<<(G * 192 + 255) / 256, 256, 0, stream>>>(P_k1, k1b, k1_gn, k1_bt, z1, G, 192, 2, 192, 0, 2);
  gemm_sk_kernel<<<dim3(G / 16, 2, 2), 256, 0, stream>>>(z1, k2W, P_k2, G, 96, 192, 96);
  epilogue_kernel<<<(G * 96 + 255) / 256, 256, 0, stream>>>(P_k2, k2b, k2_gn, k2_bt, z2, G, 96, 2, 96, 0, 2);
  gemm_sk_kernel<<<dim3(G / 16, 1, 1), 256, 0, stream>>>(z2, k3W, P_k3, G, 12, 96, 96);
  epilogue_kernel<<<(G * 12 + 255) / 256, 256, 0, stream>>>(P_k3, k3b, nullptr, nullptr, (float*)d_out, G, 12, 1, 12, 0, 0);
}

// Round 3
// 733.825 us; speedup vs baseline: 1.8527x; 1.3326x over previous
//
#include <hip/hip_runtime.h>
#include <hip/hip_bf16.h>
#include <math.h>

#define NHEAD 4
#define HC 256

typedef short short8 __attribute__((ext_vector_type(8)));
typedef float f32x4 __attribute__((ext_vector_type(4)));

// ---------------- fp32 -> bf16 (RNE) ----------------
__global__ void f32_to_bf16_kernel(const float* __restrict__ in,
                                   __hip_bfloat16* __restrict__ out, long n)
{
  long i = ((long)blockIdx.x * blockDim.x + threadIdx.x) * 4;
  if (i + 3 < n) {
#pragma unroll
    for (int j = 0; j < 4; ++j) out[i + j] = __float2bfloat16(in[i + j]);
  } else {
    for (long j = i; j < n; ++j) out[j] = __float2bfloat16(in[j]);
  }
}

// WT[n][k] = bf16(n<256 ? Wl[k*256+n] : Wr[k*256+n-256]);  WT is [512][K]
__global__ void wcat_kernel(const float* __restrict__ Wl, const float* __restrict__ Wr,
                            __hip_bfloat16* __restrict__ WT, int K)
{
  int idx = blockIdx.x * 256 + threadIdx.x;
  if (idx >= 512 * K) return;
  int n = idx / K, k = idx - n * K;
  float v = (n < 256) ? Wl[(long)k * 256 + n] : Wr[(long)k * 256 + (n - 256)];
  WT[idx] = __float2bfloat16(v);
}

// ---------------- bf16 MFMA GEMM: C[M][512] = A[M][K] @ W[K][512] + bias ----
// BT is n-major [512][K]. Tile 128(M) x 64(N), block = 4 waves, K-chunk 32.
__global__ __launch_bounds__(256) void gemm_mfma_kernel(
    const __hip_bfloat16* __restrict__ A, const __hip_bfloat16* __restrict__ BT,
    const float* __restrict__ bl, const float* __restrict__ br,
    float* __restrict__ C, int M, int K)
{
  __shared__ short As[128 * 40];
  __shared__ short Bs[64 * 40];
  int bm = blockIdx.x * 128, bn = blockIdx.y * 64;
  int t = threadIdx.x;
  int w = t >> 6, l = t & 63;
  int quad = l >> 4, l16 = l & 15;
  int col8 = (t & 3) * 8;

  f32x4 acc[2][4];
#pragma unroll
  for (int i = 0; i < 2; ++i)
#pragma unroll
    for (int j = 0; j < 4; ++j) acc[i][j] = (f32x4){0.f, 0.f, 0.f, 0.f};

  for (int k0 = 0; k0 < K; k0 += 32) {
#pragma unroll
    for (int p = 0; p < 2; ++p) {
      int row = (t >> 2) + p * 64;
      *(short8*)&As[row * 40 + col8] =
          *(const short8*)(const void*)&A[(long)(bm + row) * K + k0 + col8];
    }
    {
      int n = t >> 2;
      *(short8*)&Bs[n * 40 + col8] =
          *(const short8*)(const void*)&BT[(long)(bn + n) * K + k0 + col8];
    }
    __syncthreads();
    short8 af[2], bf[4];
#pragma unroll
    for (int mt = 0; mt < 2; ++mt)
      af[mt] = *(short8*)&As[(w * 32 + mt * 16 + l16) * 40 + quad * 8];
#pragma unroll
    for (int nt = 0; nt < 4; ++nt)
      bf[nt] = *(short8*)&Bs[(nt * 16 + l16) * 40 + quad * 8];
#pragma unroll
    for (int mt = 0; mt < 2; ++mt)
#pragma unroll
      for (int nt = 0; nt < 4; ++nt)
        acc[mt][nt] = __builtin_amdgcn_mfma_f32_16x16x32_bf16(af[mt], bf[nt], acc[mt][nt], 0, 0, 0);
    __syncthreads();
  }
#pragma unroll
  for (int mt = 0; mt < 2; ++mt)
#pragma unroll
    for (int nt = 0; nt < 4; ++nt) {
      int col = bn + nt * 16 + l16;
      float b = (col < 256) ? bl[col] : br[col - 256];
#pragma unroll
      for (int r = 0; r < 4; ++r) {
        int row = bm + w * 32 + mt * 16 + quad * 4 + r;
        C[(long)row * 512 + col] = acc[mt][nt][r] + b;
      }
    }
}

// ---------------- skinny GEMM with split-K -> partial slices ----------------
__global__ __launch_bounds__(256) void gemm_sk_kernel(
    const float* __restrict__ A, const float* __restrict__ B,
    float* __restrict__ P, int M, int N, int K, int Kc)
{
  __shared__ float As[16][17];
  __shared__ float Bs[16][65];
  int bm = blockIdx.x * 16, bn = blockIdx.y * 64;
  int s = blockIdx.z;
  int kb = s * Kc;
  int ke = min(K, kb + Kc);
  int tid = threadIdx.x;
  int tc = tid & 63;
  int trq = tid >> 6;
  int ar = tid >> 4;
  int ak = tid & 15;
  float acc[4] = {0.f, 0.f, 0.f, 0.f};

  for (int k0 = kb; k0 < ke; k0 += 16) {
    int gm = bm + ar, gk = k0 + ak;
    As[ak][ar] = (gm < M && gk < ke) ? A[(long)gm * K + gk] : 0.f;
    int gn = bn + tc;
#pragma unroll
    for (int i = 0; i < 4; ++i) {
      int kk = trq * 4 + i;
      int gkb = k0 + kk;
      Bs[kk][tc] = (gkb < ke && gn < N) ? B[(long)gkb * N + gn] : 0.f;
    }
    __syncthreads();
#pragma unroll
    for (int kk = 0; kk < 16; ++kk) {
      float b = Bs[kk][tc];
#pragma unroll
      for (int i = 0; i < 4; ++i) acc[i] = fmaf(As[kk][trq * 4 + i], b, acc[i]);
    }
    __syncthreads();
  }
  int col = bn + tc;
  if (col < N) {
#pragma unroll
    for (int i = 0; i < 4; ++i) {
      int row = bm + trq * 4 + i;
      if (row < M) P[(long)s * M * N + (long)row * N + col] = acc[i];
    }
  }
}

__global__ __launch_bounds__(256) void epilogue_kernel(
    const float* __restrict__ P, const float* __restrict__ bias,
    const float* __restrict__ gamma, const float* __restrict__ beta,
    float* __restrict__ Cm, int M, int N, int S, int ldc, int coloff, int mode)
{
  int idx = blockIdx.x * 256 + threadIdx.x;
  if (idx >= M * N) return;
  int row = idx / N, col = idx - row * N;
  float v = 0.f;
  for (int s = 0; s < S; ++s) v += P[(long)s * M * N + idx];
  v += bias[col];
  if (mode >= 1) v = fmaxf(v, 0.f);
  if (mode == 2) {
    const float inv = rsqrtf(1.f + 1e-5f);
    v = v * (gamma[col] * inv) + beta[col];
  }
  Cm[(long)row * ldc + coloff + col] = v;
}

// ---------------- CSR build ----------------
__global__ void deg_count_kernel(const int* __restrict__ dst, int* __restrict__ deg, int E)
{
  int e = blockIdx.x * blockDim.x + threadIdx.x;
  if (e < E) atomicAdd(&deg[dst[e]], 1);
}

__global__ __launch_bounds__(1024) void scan_kernel(
    const int* __restrict__ deg, int* __restrict__ ptr, int* __restrict__ cursor, int N)
{
  __shared__ int sums[1024];
  int t = threadIdx.x;
  int base = t * 32;
  int local[32];
  int s = 0;
#pragma unroll
  for (int i = 0; i < 32; ++i) {
    int v = (base + i < N) ? deg[base + i] : 0;
    local[i] = v; s += v;
  }
  sums[t] = s;
  __syncthreads();
  for (int off = 1; off < 1024; off <<= 1) {
    int v = (t >= off) ? sums[t - off] : 0;
    __syncthreads();
    sums[t] += v;
    __syncthreads();
  }
  int excl = sums[t] - s;
  for (int i = 0; i < 32; ++i) {
    if (base + i < N) { ptr[base + i] = excl; cursor[base + i] = excl; excl += local[i]; }
  }
  if (t == 1023) ptr[N] = sums[1023];
}

__global__ void fill_kernel(const int* __restrict__ dst, int* __restrict__ cursor,
                            int* __restrict__ eid, int E)
{
  int e = blockIdx.x * blockDim.x + threadIdx.x;
  if (e < E) {
    int pos = atomicAdd(&cursor[dst[e]], 1);
    eid[pos] = e;
  }
}

// ---------------- GATv2 aggregation: one wave per node ----------------
// xl/xr live in one [N][512] buffer (ldx=512); out is bf16 (obf=1) or fp32.
__global__ __launch_bounds__(256) void gat_kernel(
    const float* __restrict__ xl, const float* __restrict__ xr, int ldx,
    const float* __restrict__ edge_attr, const int* __restrict__ src_idx,
    const int* __restrict__ csr_ptr, const int* __restrict__ csr_eid,
    const float* __restrict__ We, const float* __restrict__ att,
    const float* __restrict__ bias, void* __restrict__ out, int obf, int N)
{
  int lane = threadIdx.x & 63;
  int node = blockIdx.x * 4 + (threadIdx.x >> 6);
  if (node >= N) return;

  float attv[NHEAD], xri[NHEAD], WeR[8][NHEAD];
#pragma unroll
  for (int h = 0; h < NHEAD; ++h) {
    attv[h] = att[h * 64 + lane];
    xri[h] = xr[(long)node * ldx + h * 64 + lane];
  }
#pragma unroll
  for (int d = 0; d < 8; ++d)
#pragma unroll
    for (int h = 0; h < NHEAD; ++h) WeR[d][h] = We[d * HC + h * 64 + lane];

  float rmax[NHEAD], rsum[NHEAD], acc[NHEAD];
#pragma unroll
  for (int h = 0; h < NHEAD; ++h) { rmax[h] = -INFINITY; rsum[h] = 0.f; acc[h] = 0.f; }
  float ea_sum[8];
#pragma unroll
  for (int d = 0; d < 8; ++d) ea_sum[d] = 0.f;

  int p0 = csr_ptr[node], p1 = csr_ptr[node + 1];

  for (int k = p0; k <= p1; ++k) {   // k==p1 is the self loop
    int s;
    float ea[8];
    if (k < p1) {
      int e = csr_eid[k];
      s = src_idx[e];
#pragma unroll
      for (int d = 0; d < 8; ++d) { ea[d] = edge_attr[(long)e * 8 + d]; ea_sum[d] += ea[d]; }
    } else {
      s = node;
      float invd = 1.f / (float)((p1 - p0) > 1 ? (p1 - p0) : 1);
#pragma unroll
      for (int d = 0; d < 8; ++d) ea[d] = ea_sum[d] * invd;
    }
    float xls[NHEAD], logit[NHEAD];
#pragma unroll
    for (int h = 0; h < NHEAD; ++h) xls[h] = xl[(long)s * ldx + h * 64 + lane];
#pragma unroll
    for (int h = 0; h < NHEAD; ++h) {
      float ee = 0.f;
#pragma unroll
      for (int d = 0; d < 8; ++d) ee = fmaf(ea[d], WeR[d][h], ee);
      float m = xls[h] + xri[h] + ee;
      m = (m > 0.f) ? m : 0.2f * m;
      float t = m * attv[h];
#pragma unroll
      for (int off = 32; off > 0; off >>= 1) t += __shfl_xor(t, off, 64);
      logit[h] = t;
    }
#pragma unroll
    for (int h = 0; h < NHEAD; ++h) {
      float nm = fmaxf(rmax[h], logit[h]);
      float sc = __expf(rmax[h] - nm);
      float p = __expf(logit[h] - nm);
      rsum[h] = rsum[h] * sc + p;
      acc[h] = fmaf(p, xls[h], acc[h] * sc);
      rmax[h] = nm;
    }
  }
#pragma unroll
  for (int h = 0; h < NHEAD; ++h) {
    float v = fmaxf(acc[h] / rsum[h] + bias[h * 64 + lane], 0.f);
    if (obf)
      ((__hip_bfloat16*)out)[(long)node * HC + h * 64 + lane] = __float2bfloat16(v);
    else
      ((float*)out)[(long)node * HC + h * 64 + lane] = v;
  }
}

// ---------------- global max pool ----------------
__global__ void pool_kernel(const float* __restrict__ h, const int* __restrict__ batch,
                            unsigned int* __restrict__ xg, long total)
{
  long i = (long)blockIdx.x * blockDim.x + threadIdx.x;
  if (i < total) {
    int node = (int)(i >> 8);
    int col = (int)(i & 255);
    atomicMax(&xg[(long)batch[node] * HC + col], __float_as_uint(h[i]));
  }
}

extern "C" void kernel_launch(void* const* d_in, const int* in_sizes, int n_in,
                              void* d_out, int out_size, void* d_ws, size_t ws_size,
                              hipStream_t stream)
{
  const float* x          = (const float*)d_in[0];
  const int*   edge_index = (const int*)d_in[1];
  const float* edge_attr  = (const float*)d_in[2];
  const int*   batch      = (const int*)d_in[3];
  const float* fp         = (const float*)d_in[4];
  const float* desc       = (const float*)d_in[5];
  const float *c1_Wl = (const float*)d_in[6],  *c1_bl = (const float*)d_in[7],
              *c1_Wr = (const float*)d_in[8],  *c1_br = (const float*)d_in[9],
              *c1_We = (const float*)d_in[10], *c1_att = (const float*)d_in[11],
              *c1_bias = (const float*)d_in[12];
  const float *c2_Wl = (const float*)d_in[13], *c2_bl = (const float*)d_in[14],
              *c2_Wr = (const float*)d_in[15], *c2_br = (const float*)d_in[16],
              *c2_We = (const float*)d_in[17], *c2_att = (const float*)d_in[18],
              *c2_bias = (const float*)d_in[19];
  const float *gW = (const float*)d_in[20], *gb = (const float*)d_in[21],
              *g_gn = (const float*)d_in[22], *g_bt = (const float*)d_in[23];
  const float *fW = (const float*)d_in[24], *fb = (const float*)d_in[25],
              *f_gn = (const float*)d_in[26], *f_bt = (const float*)d_in[27];
  const float *dW = (const float*)d_in[28], *db = (const float*)d_in[29],
              *d_gn = (const float*)d_in[30], *d_bt = (const float*)d_in[31];
  const float *k1W = (const float*)d_in[32], *k1b = (const float*)d_in[33],
              *k1_gn = (const float*)d_in[34], *k1_bt = (const float*)d_in[35];
  const float *k2W = (const float*)d_in[36], *k2b = (const float*)d_in[37],
              *k2_gn = (const float*)d_in[38], *k2_bt = (const float*)d_in[39];
  const float *k3W = (const float*)d_in[40], *k3b = (const float*)d_in[41];

  const int N = in_sizes[0] / 32;       // 32768
  const int E = in_sizes[1] / 2;        // 262144
  const int G = in_sizes[4] / 2048;     // 1024
  const int FIN = 32, FPIN = 2048;
  const int DIN = in_sizes[5] / G;      // 200

  char* ws = (char*)d_ws;
  size_t off = 0;
  auto alloc = [&](size_t bytes) {
    void* p = ws + off;
    off = (off + bytes + 255) & ~(size_t)255;
    return p;
  };
  float* xlxr    = (float*)alloc((size_t)N * 512 * 4);            // 64 MB
  __hip_bfloat16* hb1 = (__hip_bfloat16*)alloc((size_t)N * HC * 2); // 16 MB
  float* hbuf    = (float*)alloc((size_t)N * HC * 4);             // 32 MB
  __hip_bfloat16* xbf = (__hip_bfloat16*)alloc((size_t)N * FIN * 2);
  __hip_bfloat16* wt1 = (__hip_bfloat16*)alloc((size_t)512 * FIN * 2);
  __hip_bfloat16* wt2 = (__hip_bfloat16*)alloc((size_t)512 * HC * 2);
  float* xg      = (float*)alloc((size_t)G * HC * 4);
  float* zbuf    = (float*)alloc((size_t)G * 384 * 4);
  float* z1      = (float*)alloc((size_t)G * 192 * 4);
  float* z2      = (float*)alloc((size_t)G * 96 * 4);
  int*   deg     = (int*)alloc((size_t)N * 4);
  int*   csr_ptr = (int*)alloc((size_t)(N + 1) * 4);
  int*   cursor  = (int*)alloc((size_t)N * 4);
  int*   csr_eid = (int*)alloc((size_t)E * 4);
  float* P_fp    = (float*)alloc((size_t)G * 256 * 8 * 4);
  float* P_g     = (float*)alloc((size_t)G * 64 * 4 * 4);
  float* P_d     = (float*)alloc((size_t)G * 64 * 4 * 4);
  float* P_k1    = (float*)alloc((size_t)G * 192 * 2 * 4);
  float* P_k2    = (float*)alloc((size_t)G * 96 * 2 * 4);
  float* P_k3    = (float*)alloc((size_t)G * 12 * 1 * 4);
  (void)ws_size;

  const int* srcp = edge_index;
  const int* dstp = edge_index + E;

  hipMemsetAsync(deg, 0, (size_t)N * 4, stream);
  hipMemsetAsync(xg, 0, (size_t)G * HC * 4, stream);

  // conversions (independent)
  f32_to_bf16_kernel<<<(int)(((long)N * FIN / 4 + 255) / 256), 256, 0, stream>>>(x, xbf, (long)N * FIN);
  wcat_kernel<<<(512 * FIN + 255) / 256, 256, 0, stream>>>(c1_Wl, c1_Wr, wt1, FIN);
  wcat_kernel<<<(512 * HC + 255) / 256, 256, 0, stream>>>(c2_Wl, c2_Wr, wt2, HC);

  deg_count_kernel<<<(E + 255) / 256, 256, 0, stream>>>(dstp, deg, E);
  scan_kernel<<<1, 1024, 0, stream>>>(deg, csr_ptr, cursor, N);
  fill_kernel<<<(E + 255) / 256, 256, 0, stream>>>(dstp, cursor, csr_eid, E);

  // fp / desc branches (independent of graph pipeline)
  gemm_sk_kernel<<<dim3(G / 16, 4, 8), 256, 0, stream>>>(fp, fW, P_fp, G, 256, FPIN, 256);
  epilogue_kernel<<<(G * 256 + 255) / 256, 256, 0, stream>>>(P_fp, fb, f_gn, f_bt, zbuf, G, 256, 8, 384, 64, 2);
  gemm_sk_kernel<<<dim3(G / 16, 1, 4), 256, 0, stream>>>(desc, dW, P_d, G, 64, DIN, 50);
  epilogue_kernel<<<(G * 64 + 255) / 256, 256, 0, stream>>>(P_d, db, d_gn, d_bt, zbuf, G, 64, 4, 384, 320, 2);

  // layer 1: fused xl|xr transform (MFMA), then GAT -> bf16
  gemm_mfma_kernel<<<dim3(N / 128, 8), 256, 0, stream>>>(xbf, wt1, c1_bl, c1_br, xlxr, N, FIN);
  gat_kernel<<<(N + 3) / 4, 256, 0, stream>>>(xlxr, xlxr + 256, 512, edge_attr, srcp,
                                              csr_ptr, csr_eid, c1_We, c1_att, c1_bias,
                                              hb1, 1, N);
  // layer 2: fused transform (MFMA), then GAT -> fp32
  gemm_mfma_kernel<<<dim3(N / 128, 8), 256, 0, stream>>>(hb1, wt2, c2_bl, c2_br, xlxr, N, HC);
  gat_kernel<<<(N + 3) / 4, 256, 0, stream>>>(xlxr, xlxr + 256, 512, edge_attr, srcp,
                                              csr_ptr, csr_eid, c2_We, c2_att, c2_bias,
                                              hbuf, 0, N);

  long total = (long)N * HC;
  pool_kernel<<<(int)((total + 255) / 256), 256, 0, stream>>>(hbuf, batch, (unsigned int*)xg, total);

  // g branch (needs xg)
  gemm_sk_kernel<<<dim3(G / 16, 1, 4), 256, 0, stream>>>(xg, gW, P_g, G, 64, HC, 64);
  epilogue_kernel<<<(G * 64 + 255) / 256, 256, 0, stream>>>(P_g, gb, g_gn, g_bt, zbuf, G, 64, 4, 384, 0, 2);

  // MLP head
  gemm_sk_kernel<<<dim3(G / 16, 3, 2), 256, 0, stream>>>(zbuf, k1W, P_k1, G, 192, 384, 192);
  epilogue_kernel<<<(G * 192 + 255) / 256, 256, 0, stream>>>(P_k1, k1b, k1_gn, k1_bt, z1, G, 192, 2, 192, 0, 2);
  gemm_sk_kernel<<<dim3(G / 16, 2, 2), 256, 0, stream>>>(z1, k2W, P_k2, G, 96, 192, 96);
  epilogue_kernel<<<(G * 96 + 255) / 256, 256, 0, stream>>>(P_k2, k2b, k2_gn, k2_bt, z2, G, 96, 2, 96, 0, 2);
  gemm_sk_kernel<<<dim3(G / 16, 1, 1), 256, 0, stream>>>(z2, k3W, P_k3, G, 12, 96, 96);
  epilogue_kernel<<<(G * 12 + 255) / 256, 256, 0, stream>>>(P_k3, k3b, nullptr, nullptr, (float*)d_out, G, 12, 1, 12, 0, 0);
}

// Round 4
// 662.614 us; speedup vs baseline: 2.0518x; 1.1075x over previous
//
#include <hip/hip_runtime.h>
#include <hip/hip_bf16.h>
#include <math.h>

#define NHEAD 4
#define HC 256

typedef short short8 __attribute__((ext_vector_type(8)));
typedef short short4v __attribute__((ext_vector_type(4)));
typedef float f32x4 __attribute__((ext_vector_type(4)));

// ---------------- fp32 -> bf16 (RNE) ----------------
__global__ void f32_to_bf16_kernel(const float* __restrict__ in,
                                   __hip_bfloat16* __restrict__ out, long n)
{
  long i = ((long)blockIdx.x * blockDim.x + threadIdx.x) * 4;
  if (i + 3 < n) {
#pragma unroll
    for (int j = 0; j < 4; ++j) out[i + j] = __float2bfloat16(in[i + j]);
  } else {
    for (long j = i; j < n; ++j) out[j] = __float2bfloat16(in[j]);
  }
}

// WT[n][k] = bf16(n<256 ? Wl[k*256+n] : Wr[k*256+n-256]);  WT is [512][K]
__global__ void wcat_kernel(const float* __restrict__ Wl, const float* __restrict__ Wr,
                            __hip_bfloat16* __restrict__ WT, int K)
{
  int idx = blockIdx.x * 256 + threadIdx.x;
  if (idx >= 512 * K) return;
  int n = idx / K, k = idx - n * K;
  float v = (n < 256) ? Wl[(long)k * 256 + n] : Wr[(long)k * 256 + (n - 256)];
  WT[idx] = __float2bfloat16(v);
}

// ---------------- bf16 MFMA GEMM: C[M][512] = A[M][K] @ W[K][512] + bias ----
__global__ __launch_bounds__(256) void gemm_mfma_kernel(
    const __hip_bfloat16* __restrict__ A, const __hip_bfloat16* __restrict__ BT,
    const float* __restrict__ bl, const float* __restrict__ br,
    float* __restrict__ C, int M, int K)
{
  __shared__ short As[128 * 40];
  __shared__ short Bs[64 * 40];
  int bm = blockIdx.x * 128, bn = blockIdx.y * 64;
  int t = threadIdx.x;
  int w = t >> 6, l = t & 63;
  int quad = l >> 4, l16 = l & 15;
  int col8 = (t & 3) * 8;

  f32x4 acc[2][4];
#pragma unroll
  for (int i = 0; i < 2; ++i)
#pragma unroll
    for (int j = 0; j < 4; ++j) acc[i][j] = (f32x4){0.f, 0.f, 0.f, 0.f};

  for (int k0 = 0; k0 < K; k0 += 32) {
#pragma unroll
    for (int p = 0; p < 2; ++p) {
      int row = (t >> 2) + p * 64;
      *(short8*)&As[row * 40 + col8] =
          *(const short8*)(const void*)&A[(long)(bm + row) * K + k0 + col8];
    }
    {
      int n = t >> 2;
      *(short8*)&Bs[n * 40 + col8] =
          *(const short8*)(const void*)&BT[(long)(bn + n) * K + k0 + col8];
    }
    __syncthreads();
    short8 af[2], bf[4];
#pragma unroll
    for (int mt = 0; mt < 2; ++mt)
      af[mt] = *(short8*)&As[(w * 32 + mt * 16 + l16) * 40 + quad * 8];
#pragma unroll
    for (int nt = 0; nt < 4; ++nt)
      bf[nt] = *(short8*)&Bs[(nt * 16 + l16) * 40 + quad * 8];
#pragma unroll
    for (int mt = 0; mt < 2; ++mt)
#pragma unroll
      for (int nt = 0; nt < 4; ++nt)
        acc[mt][nt] = __builtin_amdgcn_mfma_f32_16x16x32_bf16(af[mt], bf[nt], acc[mt][nt], 0, 0, 0);
    __syncthreads();
  }
#pragma unroll
  for (int mt = 0; mt < 2; ++mt)
#pragma unroll
    for (int nt = 0; nt < 4; ++nt) {
      int col = bn + nt * 16 + l16;
      float b = (col < 256) ? bl[col] : br[col - 256];
#pragma unroll
      for (int r = 0; r < 4; ++r) {
        int row = bm + w * 32 + mt * 16 + quad * 4 + r;
        C[(long)row * 512 + col] = acc[mt][nt][r] + b;
      }
    }
}

// ---------------- skinny GEMM with split-K (fp branch) ----------------
__global__ __launch_bounds__(256) void gemm_sk_kernel(
    const float* __restrict__ A, const float* __restrict__ B,
    float* __restrict__ P, int M, int N, int K, int Kc)
{
  __shared__ float As[16][17];
  __shared__ float Bs[16][65];
  int bm = blockIdx.x * 16, bn = blockIdx.y * 64;
  int s = blockIdx.z;
  int kb = s * Kc;
  int ke = min(K, kb + Kc);
  int tid = threadIdx.x;
  int tc = tid & 63;
  int trq = tid >> 6;
  int ar = tid >> 4;
  int ak = tid & 15;
  float acc[4] = {0.f, 0.f, 0.f, 0.f};

  for (int k0 = kb; k0 < ke; k0 += 16) {
    int gm = bm + ar, gk = k0 + ak;
    As[ak][ar] = (gm < M && gk < ke) ? A[(long)gm * K + gk] : 0.f;
    int gn = bn + tc;
#pragma unroll
    for (int i = 0; i < 4; ++i) {
      int kk = trq * 4 + i;
      int gkb = k0 + kk;
      Bs[kk][tc] = (gkb < ke && gn < N) ? B[(long)gkb * N + gn] : 0.f;
    }
    __syncthreads();
#pragma unroll
    for (int kk = 0; kk < 16; ++kk) {
      float b = Bs[kk][tc];
#pragma unroll
      for (int i = 0; i < 4; ++i) acc[i] = fmaf(As[kk][trq * 4 + i], b, acc[i]);
    }
    __syncthreads();
  }
  int col = bn + tc;
  if (col < N) {
#pragma unroll
    for (int i = 0; i < 4; ++i) {
      int row = bm + trq * 4 + i;
      if (row < M) P[(long)s * M * N + (long)row * N + col] = acc[i];
    }
  }
}

__global__ __launch_bounds__(256) void epilogue_kernel(
    const float* __restrict__ P, const float* __restrict__ bias,
    const float* __restrict__ gamma, const float* __restrict__ beta,
    float* __restrict__ Cm, int M, int N, int S, int ldc, int coloff, int mode)
{
  int idx = blockIdx.x * 256 + threadIdx.x;
  if (idx >= M * N) return;
  int row = idx / N, col = idx - row * N;
  float v = 0.f;
  for (int s = 0; s < S; ++s) v += P[(long)s * M * N + idx];
  v += bias[col];
  if (mode >= 1) v = fmaxf(v, 0.f);
  if (mode == 2) {
    const float inv = rsqrtf(1.f + 1e-5f);
    v = v * (gamma[col] * inv) + beta[col];
  }
  Cm[(long)row * ldc + coloff + col] = v;
}

// -------- fused inner-product dense layer: out = bn(relu(A@W + b)) --------
// A is [M][K] contiguous (lda == K); W is [K][Ncols]; one thread per output.
__global__ __launch_bounds__(256) void dense_kernel(
    const float* __restrict__ A, const float* __restrict__ W,
    const float* __restrict__ bias, const float* __restrict__ gamma,
    const float* __restrict__ beta, float* __restrict__ out,
    int M, int Ncols, int K, int ldc, int coloff, int mode)
{
  int idx = blockIdx.x * 256 + threadIdx.x;
  if (idx >= M * Ncols) return;
  int row = idx / Ncols, col = idx - row * Ncols;
  const float* a = A + (long)row * K;
  float acc = 0.f;
#pragma unroll 4
  for (int k = 0; k < K; ++k) acc = fmaf(a[k], W[(long)k * Ncols + col], acc);
  acc += bias[col];
  if (mode >= 1) acc = fmaxf(acc, 0.f);
  if (mode == 2) {
    const float inv = rsqrtf(1.f + 1e-5f);
    acc = acc * (gamma[col] * inv) + beta[col];
  }
  out[(long)row * ldc + coloff + col] = acc;
}

// -------- fused k2+k3 head: z1[16 rows] -> z2 (LDS) -> d_out --------
__global__ __launch_bounds__(256) void head23_kernel(
    const float* __restrict__ z1, const float* __restrict__ k2W,
    const float* __restrict__ k2b, const float* __restrict__ k2_gn,
    const float* __restrict__ k2_bt, const float* __restrict__ k3W,
    const float* __restrict__ k3b, float* __restrict__ out)
{
  __shared__ float s1[16 * 192];
  __shared__ float s2[16 * 96];
  int b = blockIdx.x, t = threadIdx.x;
  for (int i = t; i < 16 * 192; i += 256) s1[i] = z1[(long)b * 16 * 192 + i];
  __syncthreads();
  const float inv = rsqrtf(1.f + 1e-5f);
#pragma unroll
  for (int j = 0; j < 6; ++j) {
    int idx = j * 256 + t;
    int row = idx / 96, col = idx - row * 96;
    float acc = 0.f;
#pragma unroll 4
    for (int k = 0; k < 192; ++k) acc = fmaf(s1[row * 192 + k], k2W[k * 96 + col], acc);
    acc = fmaxf(acc + k2b[col], 0.f);
    s2[idx] = acc * (k2_gn[col] * inv) + k2_bt[col];
  }
  __syncthreads();
  if (t < 192) {
    int row = t / 12, col = t - row * 12;
    float acc = 0.f;
#pragma unroll 4
    for (int k = 0; k < 96; ++k) acc = fmaf(s2[row * 96 + k], k3W[k * 12 + col], acc);
    out[(long)(b * 16 + row) * 12 + col] = acc + k3b[col];
  }
}

// ---------------- CSR build ----------------
__global__ void deg_count_kernel(const int* __restrict__ dst, int* __restrict__ deg, int E)
{
  int e = blockIdx.x * blockDim.x + threadIdx.x;
  if (e < E) atomicAdd(&deg[dst[e]], 1);
}

__global__ __launch_bounds__(1024) void scan_kernel(
    const int* __restrict__ deg, int* __restrict__ ptr, int* __restrict__ cursor, int N)
{
  __shared__ int sums[1024];
  int t = threadIdx.x;
  int base = t * 32;
  int local[32];
  int s = 0;
#pragma unroll
  for (int i = 0; i < 32; ++i) {
    int v = (base + i < N) ? deg[base + i] : 0;
    local[i] = v; s += v;
  }
  sums[t] = s;
  __syncthreads();
  for (int off = 1; off < 1024; off <<= 1) {
    int v = (t >= off) ? sums[t - off] : 0;
    __syncthreads();
    sums[t] += v;
    __syncthreads();
  }
  int excl = sums[t] - s;
  for (int i = 0; i < 32; ++i) {
    if (base + i < N) { ptr[base + i] = excl; cursor[base + i] = excl; excl += local[i]; }
  }
  if (t == 1023) ptr[N] = sums[1023];
}

__global__ void fill_kernel(const int* __restrict__ dst, int* __restrict__ cursor,
                            int* __restrict__ eid, int E)
{
  int e = blockIdx.x * blockDim.x + threadIdx.x;
  if (e < E) {
    int pos = atomicAdd(&cursor[dst[e]], 1);
    eid[pos] = e;
  }
}

// ---------------- GATv2 aggregation ----------------
// lane = head*16 + quad; each lane owns 4 channels (float4) of one head.
// 2 nodes per 128-thread block; online softmax; 1-edge software pipeline.
__global__ __launch_bounds__(128) void gat_kernel(
    const float* __restrict__ xl, const float* __restrict__ xr, int ldx,
    const float* __restrict__ edge_attr, const int* __restrict__ src_idx,
    const int* __restrict__ csr_ptr, const int* __restrict__ csr_eid,
    const float* __restrict__ We, const float* __restrict__ att,
    const float* __restrict__ bias, void* __restrict__ out, int obf, int N)
{
  int lane = threadIdx.x & 63;
  int node = blockIdx.x * 2 + (threadIdx.x >> 6);
  if (node >= N) return;
  int cbase = (lane >> 4) * 64 + (lane & 15) * 4;  // channel offset in [0,256)

  f32x4 attv = *(const f32x4*)(const void*)&att[cbase];
  f32x4 xriv = *(const f32x4*)(const void*)&xr[(long)node * ldx + cbase];
  f32x4 biasv = *(const f32x4*)(const void*)&bias[cbase];
  f32x4 WeR[8];
#pragma unroll
  for (int d = 0; d < 8; ++d)
    WeR[d] = *(const f32x4*)(const void*)&We[d * HC + cbase];

  float rmax = -INFINITY, rsum = 0.f;
  f32x4 acc = (f32x4){0.f, 0.f, 0.f, 0.f};
  f32x4 eas0 = (f32x4){0.f, 0.f, 0.f, 0.f};
  f32x4 eas1 = (f32x4){0.f, 0.f, 0.f, 0.f};

  int p0 = csr_ptr[node], p1 = csr_ptr[node + 1];
  f32x4 xls_self = *(const f32x4*)(const void*)&xl[(long)node * ldx + cbase];

  auto edge_compute = [&](f32x4 xls, f32x4 ea0, f32x4 ea1) {
    float t = 0.f;
#pragma unroll
    for (int r = 0; r < 4; ++r) {
      float ee = 0.f;
#pragma unroll
      for (int d = 0; d < 4; ++d) ee = fmaf(ea0[d], WeR[d][r], ee);
#pragma unroll
      for (int d = 0; d < 4; ++d) ee = fmaf(ea1[d], WeR[d + 4][r], ee);
      float m = xls[r] + xriv[r] + ee;
      m = (m > 0.f) ? m : 0.2f * m;
      t = fmaf(m, attv[r], t);
    }
    t += __shfl_xor(t, 1, 64);
    t += __shfl_xor(t, 2, 64);
    t += __shfl_xor(t, 4, 64);
    t += __shfl_xor(t, 8, 64);
    float nm = fmaxf(rmax, t);
    float sc = __expf(rmax - nm);
    float p = __expf(t - nm);
    rmax = nm;
    rsum = rsum * sc + p;
#pragma unroll
    for (int r = 0; r < 4; ++r) acc[r] = fmaf(p, xls[r], acc[r] * sc);
  };

  // prefetch first edge
  f32x4 xls_n, ea0_n, ea1_n;
  if (p0 < p1) {
    int e = csr_eid[p0];
    int s = src_idx[e];
    ea0_n = *(const f32x4*)(const void*)&edge_attr[(long)e * 8];
    ea1_n = *(const f32x4*)(const void*)&edge_attr[(long)e * 8 + 4];
    xls_n = *(const f32x4*)(const void*)&xl[(long)s * ldx + cbase];
  }
  for (int k = p0; k < p1; ++k) {
    f32x4 xls = xls_n, ea0 = ea0_n, ea1 = ea1_n;
    if (k + 1 < p1) {
      int e2 = csr_eid[k + 1];
      int s2 = src_idx[e2];
      ea0_n = *(const f32x4*)(const void*)&edge_attr[(long)e2 * 8];
      ea1_n = *(const f32x4*)(const void*)&edge_attr[(long)e2 * 8 + 4];
      xls_n = *(const f32x4*)(const void*)&xl[(long)s2 * ldx + cbase];
    }
    eas0 += ea0;
    eas1 += ea1;
    edge_compute(xls, ea0, ea1);
  }
  // self loop with mean edge_attr
  int deg = p1 - p0;
  float invd = 1.f / (float)(deg > 1 ? deg : 1);
  edge_compute(xls_self, eas0 * invd, eas1 * invd);

  float invs = 1.f / rsum;
  f32x4 v;
#pragma unroll
  for (int r = 0; r < 4; ++r) v[r] = fmaxf(acc[r] * invs + biasv[r], 0.f);
  if (obf) {
    short4v pk;
#pragma unroll
    for (int r = 0; r < 4; ++r) {
      __hip_bfloat16 hv = __float2bfloat16(v[r]);
      pk[r] = *(short*)&hv;
    }
    *(short4v*)&((__hip_bfloat16*)out)[(long)node * HC + cbase] = pk;
  } else {
    *(f32x4*)&((float*)out)[(long)node * HC + cbase] = v;
  }
}

// ---------------- segmented global max pool (batch sorted, N/G nodes/graph) --
__global__ __launch_bounds__(256) void pool_seg_kernel(
    const float* __restrict__ h, float* __restrict__ xg, int npg)
{
  int g = blockIdx.x, c = threadIdx.x;
  const float* base = h + (long)g * npg * HC + c;
  float m = -INFINITY;
#pragma unroll 4
  for (int i = 0; i < npg; ++i) m = fmaxf(m, base[(long)i * HC]);
  xg[(long)g * HC + c] = m;
}

extern "C" void kernel_launch(void* const* d_in, const int* in_sizes, int n_in,
                              void* d_out, int out_size, void* d_ws, size_t ws_size,
                              hipStream_t stream)
{
  const float* x          = (const float*)d_in[0];
  const int*   edge_index = (const int*)d_in[1];
  const float* edge_attr  = (const float*)d_in[2];
  const int*   batch      = (const int*)d_in[3];
  const float* fp         = (const float*)d_in[4];
  const float* desc       = (const float*)d_in[5];
  const float *c1_Wl = (const float*)d_in[6],  *c1_bl = (const float*)d_in[7],
              *c1_Wr = (const float*)d_in[8],  *c1_br = (const float*)d_in[9],
              *c1_We = (const float*)d_in[10], *c1_att = (const float*)d_in[11],
              *c1_bias = (const float*)d_in[12];
  const float *c2_Wl = (const float*)d_in[13], *c2_bl = (const float*)d_in[14],
              *c2_Wr = (const float*)d_in[15], *c2_br = (const float*)d_in[16],
              *c2_We = (const float*)d_in[17], *c2_att = (const float*)d_in[18],
              *c2_bias = (const float*)d_in[19];
  const float *gW = (const float*)d_in[20], *gb = (const float*)d_in[21],
              *g_gn = (const float*)d_in[22], *g_bt = (const float*)d_in[23];
  const float *fW = (const float*)d_in[24], *fb = (const float*)d_in[25],
              *f_gn = (const float*)d_in[26], *f_bt = (const float*)d_in[27];
  const float *dW = (const float*)d_in[28], *db = (const float*)d_in[29],
              *d_gn = (const float*)d_in[30], *d_bt = (const float*)d_in[31];
  const float *k1W = (const float*)d_in[32], *k1b = (const float*)d_in[33],
              *k1_gn = (const float*)d_in[34], *k1_bt = (const float*)d_in[35];
  const float *k2W = (const float*)d_in[36], *k2b = (const float*)d_in[37],
              *k2_gn = (const float*)d_in[38], *k2_bt = (const float*)d_in[39];
  const float *k3W = (const float*)d_in[40], *k3b = (const float*)d_in[41];
  (void)batch;

  const int N = in_sizes[0] / 32;       // 32768
  const int E = in_sizes[1] / 2;        // 262144
  const int G = in_sizes[4] / 2048;     // 1024
  const int FIN = 32, FPIN = 2048;
  const int DIN = in_sizes[5] / G;      // 200

  char* ws = (char*)d_ws;
  size_t off = 0;
  auto alloc = [&](size_t bytes) {
    void* p = ws + off;
    off = (off + bytes + 255) & ~(size_t)255;
    return p;
  };
  float* xlxr    = (float*)alloc((size_t)N * 512 * 4);              // 64 MB
  __hip_bfloat16* hb1 = (__hip_bfloat16*)alloc((size_t)N * HC * 2); // 16 MB
  float* hbuf    = (float*)alloc((size_t)N * HC * 4);               // 32 MB
  __hip_bfloat16* xbf = (__hip_bfloat16*)alloc((size_t)N * FIN * 2);
  __hip_bfloat16* wt1 = (__hip_bfloat16*)alloc((size_t)512 * FIN * 2);
  __hip_bfloat16* wt2 = (__hip_bfloat16*)alloc((size_t)512 * HC * 2);
  float* xg      = (float*)alloc((size_t)G * HC * 4);
  float* zbuf    = (float*)alloc((size_t)G * 384 * 4);
  float* z1      = (float*)alloc((size_t)G * 192 * 4);
  int*   deg     = (int*)alloc((size_t)N * 4);
  int*   csr_ptr = (int*)alloc((size_t)(N + 1) * 4);
  int*   cursor  = (int*)alloc((size_t)N * 4);
  int*   csr_eid = (int*)alloc((size_t)E * 4);
  float* P_fp    = (float*)alloc((size_t)G * 256 * 8 * 4);
  (void)ws_size;

  const int* srcp = edge_index;
  const int* dstp = edge_index + E;

  hipMemsetAsync(deg, 0, (size_t)N * 4, stream);

  // conversions
  f32_to_bf16_kernel<<<(int)(((long)N * FIN / 4 + 255) / 256), 256, 0, stream>>>(x, xbf, (long)N * FIN);
  wcat_kernel<<<(512 * FIN + 255) / 256, 256, 0, stream>>>(c1_Wl, c1_Wr, wt1, FIN);
  wcat_kernel<<<(512 * HC + 255) / 256, 256, 0, stream>>>(c2_Wl, c2_Wr, wt2, HC);

  // CSR
  deg_count_kernel<<<(E + 255) / 256, 256, 0, stream>>>(dstp, deg, E);
  scan_kernel<<<1, 1024, 0, stream>>>(deg, csr_ptr, cursor, N);
  fill_kernel<<<(E + 255) / 256, 256, 0, stream>>>(dstp, cursor, csr_eid, E);

  // fp branch (split-K) -> zbuf[:,64:320]
  gemm_sk_kernel<<<dim3(G / 16, 4, 8), 256, 0, stream>>>(fp, fW, P_fp, G, 256, FPIN, 256);
  epilogue_kernel<<<(G * 256 + 255) / 256, 256, 0, stream>>>(P_fp, fb, f_gn, f_bt, zbuf, G, 256, 8, 384, 64, 2);
  // desc branch -> zbuf[:,320:384]
  dense_kernel<<<(G * 64 + 255) / 256, 256, 0, stream>>>(desc, dW, db, d_gn, d_bt, zbuf, G, 64, DIN, 384, 320, 2);

  // layer 1
  gemm_mfma_kernel<<<dim3(N / 128, 8), 256, 0, stream>>>(xbf, wt1, c1_bl, c1_br, xlxr, N, FIN);
  gat_kernel<<<N / 2, 128, 0, stream>>>(xlxr, xlxr + 256, 512, edge_attr, srcp,
                                        csr_ptr, csr_eid, c1_We, c1_att, c1_bias,
                                        hb1, 1, N);
  // layer 2
  gemm_mfma_kernel<<<dim3(N / 128, 8), 256, 0, stream>>>(hb1, wt2, c2_bl, c2_br, xlxr, N, HC);
  gat_kernel<<<N / 2, 128, 0, stream>>>(xlxr, xlxr + 256, 512, edge_attr, srcp,
                                        csr_ptr, csr_eid, c2_We, c2_att, c2_bias,
                                        hbuf, 0, N);

  // pool (batch is sorted, N/G nodes per graph)
  pool_seg_kernel<<<G, 256, 0, stream>>>(hbuf, xg, N / G);

  // g branch -> zbuf[:,0:64]
  dense_kernel<<<(G * 64 + 255) / 256, 256, 0, stream>>>(xg, gW, gb, g_gn, g_bt, zbuf, G, 64, HC, 384, 0, 2);

  // MLP head
  dense_kernel<<<(G * 192 + 255) / 256, 256, 0, stream>>>(zbuf, k1W, k1b, k1_gn, k1_bt, z1, G, 192, 384, 192, 0, 2);
  head23_kernel<<<G / 16, 256, 0, stream>>>(z1, k2W, k2b, k2_gn, k2_bt, k3W, k3b, (float*)d_out);
}